// Round 1
// baseline (346.977 us; speedup 1.0000x reference)
//
#include <hip/hip_runtime.h>
#include <hip/hip_bf16.h>

// DETR matcher — the reference's cost-matrix / argmin pipeline has no effect
// on the outputs (it scatters 0 into zero-initialized int arrays). The true
// output is:
//   [0       .. 810000)   : 0.0   (matched_indices, all zeros)
//   [810000  .. 1620000)  : 0.0   (tgt_idx, all zeros)
//   [1620000 .. 4860000)  : outputs_coord flat  (900*900*4 fp32)
//   [4860000 .. 8100000)  : target_boxes flat   (900*3600 fp32)
// Pure memory-bound stream: 32.4 MB written + 25.9 MB read.
//
// Roofline: 58.3 MB total traffic @ ~6.3 TB/s achievable => ~9.5 us.
// Prior session measured 346.8 us => ~170 GB/s effective, which is NOT a
// plausible BW for this coalesced float4 stream. Resubmitting unchanged to
// capture rocprof counters and locate where the time actually goes.

#define ZERO4_COUNT   405000   // 1,620,000 floats / 4
#define COORD4_COUNT  810000   // 3,240,000 floats / 4
#define TOTAL4_COUNT  (ZERO4_COUNT + 2 * COORD4_COUNT)  // 2,025,000

__global__ __launch_bounds__(256) void detr_matcher_copy_kernel(
    const float4* __restrict__ coord,   // outputs_coord, 810000 float4
    const float4* __restrict__ boxes,   // target_boxes,  810000 float4
    float4* __restrict__ out)           // 2,025,000 float4
{
    int i = blockIdx.x * blockDim.x + threadIdx.x;
    if (i >= TOTAL4_COUNT) return;

    float4 v;
    if (i < ZERO4_COUNT) {
        v = make_float4(0.0f, 0.0f, 0.0f, 0.0f);
    } else if (i < ZERO4_COUNT + COORD4_COUNT) {
        v = coord[i - ZERO4_COUNT];
    } else {
        v = boxes[i - (ZERO4_COUNT + COORD4_COUNT)];
    }
    out[i] = v;
}

extern "C" void kernel_launch(void* const* d_in, const int* in_sizes, int n_in,
                              void* d_out, int out_size, void* d_ws, size_t ws_size,
                              hipStream_t stream) {
    // Inputs (setup_inputs order):
    //   d_in[0] outputs_class  [900*900*92] fp32 (unused)
    //   d_in[1] outputs_coord  [900*900*4]  fp32
    //   d_in[2] target_classes [900]        int  (unused)
    //   d_in[3] target_boxes   [900*3600]   fp32
    const float4* coord = (const float4*)d_in[1];
    const float4* boxes = (const float4*)d_in[3];
    float4* out = (float4*)d_out;

    const int block = 256;
    const int grid = (TOTAL4_COUNT + block - 1) / block;  // 7911
    detr_matcher_copy_kernel<<<grid, block, 0, stream>>>(coord, boxes, out);
}